// Round 14
// baseline (152.313 us; speedup 1.0000x reference)
//
#include <hip/hip_runtime.h>
#include <hip/hip_bf16.h>

// Capsule dynamic routing, factored, MFMA, min-LDS kbig + REPLICATED w~.
// r12/r13 evidence: ~54us fixed cost F per dispatch that READS a buffer
// dirty-written by a previous dispatch AND shared by many reader blocks
// (wtil: fan-out 16). Readers with fan-out 1 (kred<-tpart, ksmall<-t1) are
// fast. Fix under test: ksmall writes 8 per-chunk COPIES of w~ with
// non-temporal stores (clean lines in LLC); each kbig block reads its own
// copy -> dirty fan-out <=1. CHROWS=256 (512thr/8wave) halves tpart so
// ws fits: 0.5+0.5+4+4 = 9MB < 9.96MB proven.

#define BB 64
#define NN 2048
#define DD 64
#define II 32
#define CHROWS 256            // rows per kbig block (8 waves x 32 rows)
#define NCH (NN / CHROWS)     // 8 chunks per batch

typedef __attribute__((ext_vector_type(8)))  short bf16x8;
typedef __attribute__((ext_vector_type(16))) float f32x16;

__device__ __forceinline__ short f2bf(float f) {
    __hip_bfloat16 h = __float2bfloat16(f);
    return *reinterpret_cast<short*>(&h);
}
__device__ __forceinline__ float bf2f(short s) {
    __hip_bfloat16 h = *reinterpret_cast<__hip_bfloat16*>(&s);
    return __bfloat162float(h);
}

// ---------------- kernel 1: spart[cb][b][d] = sum of 64 rows ----------------
__global__ __launch_bounds__(256) void ksum(const float* __restrict__ u,
                                            float* __restrict__ spart) {
    int b = blockIdx.y, cb = blockIdx.x;
    int tid = threadIdx.x, cg = tid & 15, rr = tid >> 4;
    const float4* up = reinterpret_cast<const float4*>(
        u + ((size_t)b * NN + (size_t)cb * 64 + rr) * DD) + cg;
    float4 a = {0.f, 0.f, 0.f, 0.f};
    #pragma unroll
    for (int k = 0; k < 4; ++k) {
        float4 v = up[(size_t)k * 16 * (DD / 4)];
        a.x += v.x; a.y += v.y; a.z += v.z; a.w += v.w;
    }
    __shared__ float4 red[16][16];
    red[rr][cg] = a;
    __syncthreads();
    if (rr == 0) {
        float4 s = red[0][cg];
        #pragma unroll
        for (int r = 1; r < 16; ++r) {
            s.x += red[r][cg].x; s.y += red[r][cg].y;
            s.z += red[r][cg].z; s.w += red[r][cg].w;
        }
        reinterpret_cast<float4*>(spart + ((size_t)cb * BB + b) * DD)[cg] = s;
    }
}

// ---------------- small kernel: per-(b,i) o, normalize, w~ (or squash->out) ----
// w_out gets NCH replicated copies (stride 131072 floats), non-temporal.
template <int MODE>
__global__ __launch_bounds__(512) void ksmall(const float* __restrict__ src,
                                              const float* __restrict__ W,
                                              float* __restrict__ w_out,
                                              float* __restrict__ out) {
    int b = blockIdx.x;
    int tid = threadIdx.x;
    int i = tid >> 4;
    int j = tid & 15;
    __shared__ float srow[DD];
    if (MODE == 0) {
        if (tid < DD) {
            float a = 0.f;
            for (int cb = 0; cb < 32; ++cb)
                a += src[((size_t)cb * BB + b) * DD + tid];
            srow[tid] = a;
        }
        __syncthreads();
    }
    const float* trow = (MODE == 0) ? srow : (src + ((size_t)b * II + i) * DD);
    float o = 0.f;
    #pragma unroll 8
    for (int d = 0; d < DD; ++d)
        o += trow[d] * W[d * (II * 16) + i * 16 + j];
    if (MODE == 0) o *= (1.0f / 32.0f);

    float ss = o * o;
    #pragma unroll
    for (int off = 8; off >= 1; off >>= 1)
        ss += __shfl_xor(ss, off, 16);

    if (MODE == 2) {
        float s2 = ss + 1e-7f;                       // K.epsilon
        float scale = sqrtf(s2) / (0.5f + s2);       // squash
        out[((size_t)b * II + i) * 16 + j] = scale * o;
        return;
    }

    float norm = sqrtf(fmaxf(ss, 1e-12f));           // tf l2_normalize
    float ov = o / norm;
    __shared__ float osh[II][16];
    osh[i][j] = ov;
    __syncthreads();
    #pragma unroll
    for (int k = 0; k < 4; ++k) {
        int d = j + 16 * k;
        float acc = 0.f;
        #pragma unroll
        for (int jj = 0; jj < 16; ++jj)
            acc += W[d * (II * 16) + i * 16 + jj] * osh[i][jj];
        size_t off0 = ((size_t)b * II + i) * DD + d;
        #pragma unroll
        for (int rep = 0; rep < NCH; ++rep)          // replicated, clean (NT)
            __builtin_nontemporal_store(acc, &w_out[(size_t)rep * 131072 + off0]);
    }
}

// ---------------- partial reduce: t[m] = sum_ch tpart[ch][m] ----------------
__global__ __launch_bounds__(256) void kred(const float* __restrict__ in,
                                            float* __restrict__ out) {
    int m = blockIdx.x * 256 + threadIdx.x;
    float acc = 0.f;
    #pragma unroll
    for (int ch = 0; ch < NCH; ++ch)
        acc += in[(size_t)ch * (BB * II * DD) + m];
    out[m] = acc;
}

// ---------------- big kernel: one routing pass, 8.3 KB LDS, private w~ ------
__global__ __launch_bounds__(512) void kbig(const float* __restrict__ u,
                                            const float* __restrict__ wR,
                                            float* __restrict__ tpart) {
    int b = blockIdx.y;
    int chunk = blockIdx.x;                 // 0..NCH-1
    int tid = threadIdx.x;
    int wv = tid >> 6, l = tid & 63, h = l >> 5, ln = l & 31;

    __shared__ float tlds[II][65];          // 8.3 KB — the ONLY LDS

    const float* ubase = u + (size_t)b * NN * DD;
    const float* wb = wR + (size_t)chunk * 131072 + (size_t)b * II * DD; // private copy
    int n0 = chunk * CHROWS + wv * 32;      // this wave's 32 rows

    for (int k = tid; k < II * 65; k += 512) (&tlds[0][0])[k] = 0.f;

    // ---- phase 1: C1[n][i] = sum_d u[n][d] * w~[i][d]  (A=u rows, B=w~^T) ----
    f32x16 S;
    #pragma unroll
    for (int r = 0; r < 16; ++r) S[r] = 0.f;
    #pragma unroll
    for (int kt = 0; kt < 4; ++kt) {
        int d0 = kt * 16 + h * 8;
        const float4* pa = reinterpret_cast<const float4*>(
            ubase + (size_t)(n0 + ln) * DD + d0);
        const float4* pb = reinterpret_cast<const float4*>(
            wb + (size_t)ln * DD + d0);
        float4 a0 = pa[0], a1 = pa[1];
        float4 b0 = pb[0], b1 = pb[1];
        bf16x8 A, Bv;
        A[0]=f2bf(a0.x); A[1]=f2bf(a0.y); A[2]=f2bf(a0.z); A[3]=f2bf(a0.w);
        A[4]=f2bf(a1.x); A[5]=f2bf(a1.y); A[6]=f2bf(a1.z); A[7]=f2bf(a1.w);
        Bv[0]=f2bf(b0.x); Bv[1]=f2bf(b0.y); Bv[2]=f2bf(b0.z); Bv[3]=f2bf(b0.w);
        Bv[4]=f2bf(b1.x); Bv[5]=f2bf(b1.y); Bv[6]=f2bf(b1.z); Bv[7]=f2bf(b1.w);
        S = __builtin_amdgcn_mfma_f32_32x32x16_bf16(A, Bv, S, 0, 0, 0);
    }

    // ---- softmax over i: cross-lane reduce within each 32-lane group ----
    float c[16];
    #pragma unroll
    for (int r = 0; r < 16; ++r) {
        float m = S[r];
        #pragma unroll
        for (int off = 1; off <= 16; off <<= 1) m = fmaxf(m, __shfl_xor(m, off));
        float e = __expf(S[r] - m);
        float s = e;
        #pragma unroll
        for (int off = 1; off <= 16; off <<= 1) s += __shfl_xor(s, off);
        c[r] = e / s;                       // c[n_r(h)][i=ln] in-register
    }

    // ---- phase 2: C2[i][d] = sum_n c[n][i]*u[n][d]; A=c^T from regs ----
    f32x16 G0, G1;
    #pragma unroll
    for (int r = 0; r < 16; ++r) { G0[r] = 0.f; G1[r] = 0.f; }

    #pragma unroll
    for (int t2 = 0; t2 < 2; ++t2) {
        float pc[8];
        #pragma unroll
        for (int q = 0; q < 8; ++q) pc[q] = __shfl_xor(c[8 * t2 + q], 32);
        bf16x8 Ah, Al;
        #pragma unroll
        for (int j = 0; j < 8; ++j) {
            float av = ((j >> 2) == h) ? c[8 * t2 + j] : pc[j ^ 4];
            short hi = f2bf(av);
            Ah[j] = hi;
            Al[j] = f2bf(av - bf2f(hi));
        }
        #pragma unroll
        for (int Nt = 0; Nt < 2; ++Nt) {
            bf16x8 Bh, Bl;
            #pragma unroll
            for (int j = 0; j < 8; ++j) {
                int n = t2 * 16 + h * 8 + j;
                float uv = ubase[(size_t)(n0 + n) * DD + Nt * 32 + ln];  // u column
                short hi = f2bf(uv);
                Bh[j] = hi;
                Bl[j] = f2bf(uv - bf2f(hi));
            }
            if (Nt == 0) {
                G0 = __builtin_amdgcn_mfma_f32_32x32x16_bf16(Ah, Bh, G0, 0, 0, 0);
                G0 = __builtin_amdgcn_mfma_f32_32x32x16_bf16(Al, Bh, G0, 0, 0, 0);
                G0 = __builtin_amdgcn_mfma_f32_32x32x16_bf16(Ah, Bl, G0, 0, 0, 0);
            } else {
                G1 = __builtin_amdgcn_mfma_f32_32x32x16_bf16(Ah, Bh, G1, 0, 0, 0);
                G1 = __builtin_amdgcn_mfma_f32_32x32x16_bf16(Al, Bh, G1, 0, 0, 0);
                G1 = __builtin_amdgcn_mfma_f32_32x32x16_bf16(Ah, Bl, G1, 0, 0, 0);
            }
        }
    }

    // ---- cross-wave reduce + coalesced partial store ----
    __syncthreads();
    #pragma unroll
    for (int r = 0; r < 16; ++r) {
        int irow = (r & 3) + 8 * (r >> 2) + 4 * h;
        atomicAdd(&tlds[irow][ln],      G0[r]);
        atomicAdd(&tlds[irow][32 + ln], G1[r]);
    }
    __syncthreads();
    float* dst = tpart + ((size_t)chunk * BB + b) * (II * DD);
    for (int k = tid; k < II * DD; k += 512)
        dst[k] = tlds[k >> 6][k & 63];
}

extern "C" void kernel_launch(void* const* d_in, const int* in_sizes, int n_in,
                              void* d_out, int out_size, void* d_ws, size_t ws_size,
                              hipStream_t stream) {
    const float* u = (const float*)d_in[0];     // (64, 2048, 64)
    const float* W = (const float*)d_in[1];     // (1, 64, 512)
    float* out = (float*)d_out;                 // (64, 32, 16)
    float* ws = (float*)d_ws;

    float* t1    = ws;                          // 131072 floats (0.5 MB)
    float* spart = ws + 131072;                 // 131072       (0.5 MB)
    float* wtilR = ws + 2 * 131072;             // NCH*131072   (4 MB) replicated
    float* tpart = ws + (2 + NCH) * 131072;     // NCH*131072   (4 MB)
    // total (2+2*NCH)*131072*4B = 9.0 MB < 9.96 MB proven available (r7).

    dim3 gbig(NCH, BB);
    ksum<<<dim3(32, BB), 256, 0, stream>>>(u, spart);
    ksmall<0><<<BB, 512, 0, stream>>>(spart, W, wtilR, nullptr);  // iter0
    kbig<<<gbig, 512, 0, stream>>>(u, wtilR, tpart);
    kred<<<BB * II * DD / 256, 256, 0, stream>>>(tpart, t1);
    ksmall<1><<<BB, 512, 0, stream>>>(t1, W, wtilR, nullptr);
    kbig<<<gbig, 512, 0, stream>>>(u, wtilR, tpart);
    kred<<<BB * II * DD / 256, 256, 0, stream>>>(tpart, t1);
    ksmall<2><<<BB, 512, 0, stream>>>(t1, W, nullptr, out);       // squash
}